// Round 11
// baseline (235.502 us; speedup 1.0000x reference)
//
#include <hip/hip_runtime.h>
#include <hip/hip_bf16.h>

#define GAT_ALPHA 0.2f
#define LOG2E 1.4426950408889634f

typedef float f32x4 __attribute__((ext_vector_type(4)));
typedef int   i32x4 __attribute__((ext_vector_type(4)));
typedef short bf16x8 __attribute__((ext_vector_type(8)));

static constexpr int Nn  = 2048;
static constexpr int FIN = 256;
static constexpr int FO  = 128;

static __device__ __forceinline__ unsigned short f2bf(float x) {
    __hip_bfloat16 h = __float2bfloat16(x);
    return __builtin_bit_cast(unsigned short, h);
}
static __device__ __forceinline__ float bf2f(unsigned short u) {
    unsigned int v = ((unsigned int)u) << 16;
    return __builtin_bit_cast(float, v);
}

// ---------------------------------------------------------------------------
// Kernel 0 (prep): wa = W@a (both halves). Inits md_key[8] = 0 (key of -inf).
// ---------------------------------------------------------------------------
__global__ __launch_bounds__(256) void gat_prep(
        const float* __restrict__ W, const float* __restrict__ a,
        float* __restrict__ wa, unsigned int* __restrict__ md_key)
{
    __shared__ float pr[32][8];
    __shared__ float pd[32][8];
    const int t = threadIdx.x;
    const int kl = t >> 3, seg = t & 7;
    const int k = blockIdx.x * 32 + kl;
    float ps = 0.f, pv = 0.f;
    const float* wr = W + (size_t)k * FO + seg * 16;
    #pragma unroll
    for (int f = 0; f < 16; f += 4) {
        f32x4 wv = *(const f32x4*)(wr + f);
        f32x4 as = *(const f32x4*)(a + seg * 16 + f);
        f32x4 ad = *(const f32x4*)(a + FO + seg * 16 + f);
        ps += wv[0]*as[0] + wv[1]*as[1] + wv[2]*as[2] + wv[3]*as[3];
        pv += wv[0]*ad[0] + wv[1]*ad[1] + wv[2]*ad[2] + wv[3]*ad[3];
    }
    pr[kl][seg] = ps; pd[kl][seg] = pv;
    __syncthreads();
    if (t < 32) {
        float s = 0.f, d = 0.f;
        #pragma unroll
        for (int j = 0; j < 8; ++j) { s += pr[t][j]; d += pd[t][j]; }
        wa[blockIdx.x * 32 + t]       = s;
        wa[256 + blockIdx.x * 32 + t] = d;
    }
    if (blockIdx.x == 0 && t < 8) md_key[t] = 0u;   // key(-inf)
}

// ---------------------------------------------------------------------------
// Kernel 1: Wp = bf16(h@W) in PACKED MFMA-B-fragment layout:
//   elem index ((b*64 + v)*8 + nt)*512 + lane*8 + e, where for feature f and
//   node n: v=n>>5, nt=f>>4, lane=((n>>3)&3)*16 + (f&15), e=n&7.
// s_src/s_dst fp32-exact via wa; per-batch max(s_dst) via uint atomicMax.
// ---------------------------------------------------------------------------
__global__ __launch_bounds__(256) void gat_wh(
        const float* __restrict__ h, const float* __restrict__ W,
        const float* __restrict__ wa, unsigned short* __restrict__ Wp,
        float* __restrict__ s_src, float* __restrict__ s_dst,
        unsigned int* __restrict__ md_key)
{
    __shared__ unsigned short WT[FO][264];  // [f][k] bf16, padded
    __shared__ float wal[512];
    __shared__ float sred[64][4][2];
    __shared__ float red64[64];
    const int t  = threadIdx.x;
    const int b  = blockIdx.x & 7;
    const int n0 = (blockIdx.x >> 3) << 6;

    if (t < 128) *(f32x4*)&wal[t * 4] = *(const f32x4*)&wa[t * 4];
    #pragma unroll
    for (int c = 0; c < 32; ++c) {
        int flat = c * 1024 + t * 4;
        int k = flat >> 7, f = flat & 127;
        f32x4 wv = *(const f32x4*)&W[flat];
        WT[f + 0][k] = f2bf(wv[0]);
        WT[f + 1][k] = f2bf(wv[1]);
        WT[f + 2][k] = f2bf(wv[2]);
        WT[f + 3][k] = f2bf(wv[3]);
    }
    __syncthreads();

    {
        const int row = t >> 2, seg = t & 3;
        const float* hp  = h + ((size_t)(b * Nn + n0 + row)) * FIN + seg * 64;
        const float* was = &wal[seg * 64];
        const float* wad = &wal[256 + seg * 64];
        float ps = 0.f, pv = 0.f;
        #pragma unroll
        for (int j = 0; j < 64; j += 4) {
            f32x4 hv = *(const f32x4*)(hp + j);
            f32x4 sv = *(const f32x4*)(was + j);
            f32x4 dv = *(const f32x4*)(wad + j);
            ps += hv[0]*sv[0] + hv[1]*sv[1] + hv[2]*sv[2] + hv[3]*sv[3];
            pv += hv[0]*dv[0] + hv[1]*dv[1] + hv[2]*dv[2] + hv[3]*dv[3];
        }
        sred[row][seg][0] = ps;
        sred[row][seg][1] = pv;
    }
    __syncthreads();
    if (t < 64) {
        float s = sred[t][0][0] + sred[t][1][0] + sred[t][2][0] + sred[t][3][0];
        float d = sred[t][0][1] + sred[t][1][1] + sred[t][2][1] + sred[t][3][1];
        s_src[b * Nn + n0 + t] = s;
        s_dst[b * Nn + n0 + t] = d;
        red64[t] = d;
    }
    __syncthreads();
    if (t < 16) red64[t] = fmaxf(fmaxf(red64[t], red64[t + 16]),
                                 fmaxf(red64[t + 32], red64[t + 48]));
    __syncthreads();
    if (t == 0) {
        float m = red64[0];
        #pragma unroll
        for (int j = 1; j < 16; ++j) m = fmaxf(m, red64[j]);
        unsigned int bits = __builtin_bit_cast(unsigned int, m);
        unsigned int key  = (bits & 0x80000000u) ? ~bits : (bits | 0x80000000u);
        atomicMax(md_key + b, key);
    }

    const int w = t >> 6, lane = t & 63, n16 = lane & 15, quad = lane >> 4;
    const float* ha = h + ((size_t)(b * Nn + n0 + w * 16 + n16)) * FIN + quad * 8;
    f32x4 acc[8] = {};
    #pragma unroll
    for (int ks = 0; ks < 8; ++ks) {
        f32x4 h0 = *(const f32x4*)(ha + ks * 32);
        f32x4 h1 = *(const f32x4*)(ha + ks * 32 + 4);
        bf16x8 af;
        af[0] = (short)f2bf(h0[0]); af[1] = (short)f2bf(h0[1]);
        af[2] = (short)f2bf(h0[2]); af[3] = (short)f2bf(h0[3]);
        af[4] = (short)f2bf(h1[0]); af[5] = (short)f2bf(h1[1]);
        af[6] = (short)f2bf(h1[2]); af[7] = (short)f2bf(h1[3]);
        #pragma unroll
        for (int nt = 0; nt < 8; ++nt) {
            bf16x8 bfr = *(const bf16x8*)&WT[nt * 16 + n16][ks * 32 + quad * 8];
            acc[nt] = __builtin_amdgcn_mfma_f32_16x16x32_bf16(af, bfr, acc[nt], 0, 0, 0);
        }
    }
    // packed write: element (f = nt*16+n16, n = n0 + w*16 + quad*4 + rr)
    {
        const int v      = (n0 >> 5) + (w >> 1);
        const int quad_p = ((w & 1) << 1) + (quad >> 1);
        const int eoff   = (quad & 1) << 2;
        #pragma unroll
        for (int nt = 0; nt < 8; ++nt) {
            ushort4 pk;
            pk.x = f2bf(acc[nt][0]); pk.y = f2bf(acc[nt][1]);
            pk.z = f2bf(acc[nt][2]); pk.w = f2bf(acc[nt][3]);
            size_t idx = ((((size_t)(b << 6) + v) * 8 + nt) * 64 + quad_p * 16 + n16) * 8 + eoff;
            *(ushort4*)&Wp[idx] = pk;
        }
    }
}

// ---------------------------------------------------------------------------
// Kernel 2 (v14): line-rate x low-traffic. Barrier-free, LDS-free main loop
// (v4's dataflow, measured 12 B/cy/CU) with ZERO Wp redundancy:
// 64-row blocks, 8 waves = 8 DISJOINT 32-j windows of 256-j tiles (8 tiles).
// Per wave per tile: 4 A-frags (rows i0+{0,16,32,48}+n16) computed in regs
// from direct adj loads (full-line consumption) + s_dst; 8 B-frags direct
// from packed Wp (1 KiB contiguous per wave-load); 32 MFMA into acc[4][8].
// Per-CU traffic: adj 512 KB + Wp 512 KB = 1.03 MB (vs v4's 2.5 MB, at
// v4's rate). Grid 256 = 32 i-tiles x 8 batches (batch==XCD), 1 block/CU.
// Epilogue: 4-slot LDS tree reduce (8 waves hold partials for SAME rows).
// ---------------------------------------------------------------------------
__global__ __launch_bounds__(512, 1) void gat_attn(
        const int* __restrict__ adj, const unsigned short* __restrict__ Wp,
        const float* __restrict__ s_src, const float* __restrict__ s_dst,
        const unsigned int* __restrict__ md_key, float* __restrict__ out)
{
    constexpr int AS = 132;                         // slot row stride (f32)
    __shared__ __align__(16) float red4[4][64 * AS];   // 135168 B (epilogue only)
    __shared__ float l_red[64];

    const int t = threadIdx.x, w = t >> 6, lane = t & 63;
    const int n16 = lane & 15, quad = lane >> 4;
    const int b  = blockIdx.x & 7;
    const int i0 = (blockIdx.x >> 3) << 6;

    if (t < 64) l_red[t] = 0.f;
    __syncthreads();

    const unsigned int key = md_key[b];
    const unsigned int mb_ = (key & 0x80000000u) ? (key ^ 0x80000000u) : ~key;
    const float mdb = __builtin_bit_cast(float, mb_);

    // per-lane row params for 4 fragments (rows i0 + ig*16 + n16)
    float mi[4], sL[4];
    #pragma unroll
    for (int ig = 0; ig < 4; ++ig) {
        float ssr = s_src[b * Nn + i0 + ig * 16 + n16];
        float tm  = ssr + mdb;
        mi[ig] = fmaxf(tm, GAT_ALPHA * tm) * LOG2E;     // row upper bound
        sL[ig] = ssr * LOG2E;
    }

    const int jq = (w << 5) + (quad << 3);          // lane's j offset in tile
    const int* ab = adj + ((size_t)(b * Nn + i0 + n16)) * Nn + jq;
    const float* dptr = s_dst + b * Nn + jq;
    // packed Wp: tile s, window w, frag nt at (b<<18) + s*32768 + w*4096 + nt*512 + lane*8
    const unsigned short* wpb = Wp + ((size_t)b << 18) + (w << 12) + (lane << 3);

    f32x4 acc[4][8] = {};
    float ls[4] = {0.f, 0.f, 0.f, 0.f};

    for (int s = 0; s < 8; ++s) {
        const int j0 = s << 8;
        // adj loads: 4 rows x 8 ints (full 128-B line consumed per wave-row)
        i32x4 a0[4], a1[4];
        #pragma unroll
        for (int ig = 0; ig < 4; ++ig) {
            const int* ar = ab + (size_t)(ig << 4) * Nn;
            a0[ig] = *(const i32x4*)(ar + j0);
            a1[ig] = *(const i32x4*)(ar + j0 + 4);
        }
        // B fragments: 8 x 1024-B fully-contiguous wave loads (L2/L3-hot)
        bf16x8 bfr[8];
        #pragma unroll
        for (int nt = 0; nt < 8; ++nt)
            bfr[nt] = *(const bf16x8*)(wpb + (s << 15) + (nt << 9));
        // d-values (L2-hot broadcast)
        f32x4 d0 = *(const f32x4*)(dptr + j0);
        f32x4 d1 = *(const f32x4*)(dptr + j0 + 4);

        // exp -> 4 A fragments
        bf16x8 af[4];
        #pragma unroll
        for (int ig = 0; ig < 4; ++ig) {
            #pragma unroll
            for (int j = 0; j < 4; ++j) {
                {   float u  = __builtin_fmaf(d0[j], LOG2E, sL[ig]);
                    float lr = fmaxf(u, GAT_ALPHA * u);
                    float e  = __builtin_amdgcn_exp2f(lr - mi[ig]);
                    e = (a0[ig][j] > 0) ? e : 0.f;
                    unsigned short us = f2bf(e);
                    ls[ig] += bf2f(us); af[ig][j] = (short)us; }
                {   float u  = __builtin_fmaf(d1[j], LOG2E, sL[ig]);
                    float lr = fmaxf(u, GAT_ALPHA * u);
                    float e  = __builtin_amdgcn_exp2f(lr - mi[ig]);
                    e = (a1[ig][j] > 0) ? e : 0.f;
                    unsigned short us = f2bf(e);
                    ls[ig] += bf2f(us); af[ig][4 + j] = (short)us; }
            }
        }
        // 32 MFMA
        #pragma unroll
        for (int nt = 0; nt < 8; ++nt)
            #pragma unroll
            for (int ig = 0; ig < 4; ++ig)
                acc[ig][nt] = __builtin_amdgcn_mfma_f32_16x16x32_bf16(af[ig], bfr[nt], acc[ig][nt], 0, 0, 0);
    }

    // denominator: collapse quads via shfl, 8 waves via LDS atomics
    #pragma unroll
    for (int ig = 0; ig < 4; ++ig) {
        ls[ig] += __shfl_xor(ls[ig], 16);
        ls[ig] += __shfl_xor(ls[ig], 32);
    }
    if (quad == 0) {
        #pragma unroll
        for (int ig = 0; ig < 4; ++ig)
            atomicAdd(&l_red[ig * 16 + n16], ls[ig]);
    }

    // acc reduce: waves 0-3 write slots 0-3; waves 4-7 add; store sums 4 slots
    if (w < 4) {
        float* slot = red4[w];
        #pragma unroll
        for (int ig = 0; ig < 4; ++ig)
            #pragma unroll
            for (int nt = 0; nt < 8; ++nt)
                #pragma unroll
                for (int rr = 0; rr < 4; ++rr)
                    slot[(size_t)(ig * 16 + quad * 4 + rr) * AS + nt * 16 + n16] = acc[ig][nt][rr];
    }
    __syncthreads();
    if (w >= 4) {
        float* slot = red4[w - 4];
        #pragma unroll
        for (int ig = 0; ig < 4; ++ig)
            #pragma unroll
            for (int nt = 0; nt < 8; ++nt)
                #pragma unroll
                for (int rr = 0; rr < 4; ++rr)
                    slot[(size_t)(ig * 16 + quad * 4 + rr) * AS + nt * 16 + n16] += acc[ig][nt][rr];
    }
    __syncthreads();

    // normalize + ELU + coalesced store (64 rows x 128 f)
    float* ob = out + ((size_t)(b * Nn + i0)) * FO;
    #pragma unroll
    for (int c = 0; c < 4; ++c) {
        int flat = c * 2048 + t * 4;
        int m = flat >> 7, f = flat & 127;
        f32x4 v0 = *(const f32x4*)&red4[0][(size_t)m * AS + f];
        f32x4 v1 = *(const f32x4*)&red4[1][(size_t)m * AS + f];
        f32x4 v2 = *(const f32x4*)&red4[2][(size_t)m * AS + f];
        f32x4 v3 = *(const f32x4*)&red4[3][(size_t)m * AS + f];
        float l = l_red[m];
        f32x4 o;
        #pragma unroll
        for (int j = 0; j < 4; ++j) {
            float x = (v0[j] + v1[j] + v2[j] + v3[j]) / l;
            o[j] = x > 0.f ? x : expm1f(x);
        }
        *(f32x4*)&ob[(size_t)m * FO + f] = o;
    }
}

extern "C" void kernel_launch(void* const* d_in, const int* in_sizes, int n_in,
                              void* d_out, int out_size, void* d_ws, size_t ws_size,
                              hipStream_t stream)
{
    const float* h   = (const float*)d_in[0];
    const int*   adj = (const int*)d_in[1];
    const float* W   = (const float*)d_in[2];
    const float* a   = (const float*)d_in[3];
    float* out = (float*)d_out;

    char* ws = (char*)d_ws;
    unsigned short* Wp  = (unsigned short*)ws;                    // 4 MiB packed
    float* s_src        = (float*)(ws + 4194304);                 // 8 KiB
    float* s_dst        = (float*)(ws + 4259840);                 // 8 KiB
    float* wa           = (float*)(ws + 4325376);                 // 2 KiB
    unsigned int* md_key= (unsigned int*)(ws + 4327424);          // 32 B

    hipLaunchKernelGGL(gat_prep, dim3(8),   dim3(256), 0, stream, W, a, wa, md_key);
    hipLaunchKernelGGL(gat_wh,   dim3(256), dim3(256), 0, stream, h, W, wa, Wp, s_src, s_dst, md_key);
    hipLaunchKernelGGL(gat_attn, dim3(256), dim3(512), 0, stream, adj, Wp, s_src, s_dst, md_key, out);
}